// Round 6
// baseline (51.267 us; speedup 1.0000x reference)
//
#include <hip/hip_runtime.h>
#include <stdint.h>

#define BB 512
#define TT 500
#define KK 64
#define DD 64

// One block per batch element b. No global scratch; all intermediates in LDS.
// chain dtype (bf16 vs f32) sniffed on-device from its first 64 words:
//   f32 one-hot row 0 = 64 words with exactly 1 nonzero (0x3F800000)
//   bf16 rows 0,1     = 64 words with exactly 2 nonzero (one 0x3F80 half each)
__launch_bounds__(256, 2)
__global__ void bkt_fused(const int* __restrict__ corr,
                          const uint32_t* __restrict__ chainw,
                          const float* __restrict__ embd,
                          const float* __restrict__ Wf,
                          const float* __restrict__ bias,
                          float2* __restrict__ out) {
    __shared__ float embd_s[DD][DD + 1];
    __shared__ float Wf_s[5 * DD];
    __shared__ float bias_s[5];
    __shared__ float g0s[KK], g1s[KK], t10s[KK], t11s[KK], p1s[KK];
    __shared__ int corr_s[TT];
    __shared__ uint8_t evs[TT];
    __shared__ int cnt[4][KK];
    __shared__ int startw[4][KK];
    __shared__ int segs[KK], sege[KK];
    __shared__ uint16_t lst[TT];
    __shared__ __align__(16) float out_s[TT][2];
    __shared__ int is_bf16;

    const int b = blockIdx.x;
    const int tid = threadIdx.x;
    const int w = tid >> 6, lane = tid & 63;

    // ---------- dtype sniff (wave 0; first 256 B of chain, in-bounds either way) ----------
    if (tid < 64) {
        uint32_t v = chainw[tid];
        unsigned long long m = __ballot(v != 0u);
        if (tid == 0) is_bf16 = (__popcll(m) >= 2) ? 1 : 0;
    }

    // ---------- stage weights + corr ----------
    for (int i = tid; i < DD * DD; i += 256) embd_s[i >> 6][i & 63] = embd[i];
    for (int i = tid; i < 5 * DD; i += 256) Wf_s[i] = Wf[i];
    if (tid < 5) bias_s[tid] = bias[tid];
    for (int i = tid; i < TT; i += 256) corr_s[i] = corr[b * TT + i];
    __syncthreads();

    // ---------- phase A: per-k parameters (wave 0) ----------
    if (tid < KK) {
        const int k = tid;
        float l[5];
#pragma unroll
        for (int j = 0; j < 5; ++j) {
            float s = bias_s[j];
#pragma unroll 8
            for (int d = 0; d < DD; ++d) s = fmaf(embd_s[k][d], Wf_s[j * DD + d], s);
            l[j] = s;
        }
        auto sig = [](float x) { return 1.0f / (1.0f + __expf(-x)); };
        t10s[k] = sig( 2.f * l[0]);   // p(s'=1 | s=0)
        t11s[k] = sig(-2.f * l[1]);   // p(s'=1 | s=1)
        g0s[k]  = sig( 2.f * l[2]);   // p(y=1 | s=0)
        g1s[k]  = sig(-2.f * l[3]);   // p(y=1 | s=1)
        p1s[k]  = sig( 2.f * l[4]);   // p(s=1) initial
    }

    // ---------- phase B: one-hot detect over chain[b] ----------
    if (is_bf16) {
        // row = 64 bf16 = 128 B = 8 uint4; 32 rows per iteration.
        const uint4* crow = (const uint4*)(chainw + (size_t)b * (TT * 32));
        const int u4i = tid & 7;
#pragma unroll 4
        for (int it = 0; it < 16; ++it) {
            int row = it * 32 + (tid >> 3);
            if (row < TT) {
                uint4 v = crow[row * 8 + u4i];
                uint32_t wd[4] = {v.x, v.y, v.z, v.w};
                int j = -1;
#pragma unroll
                for (int m = 0; m < 4; ++m) {
                    if ((wd[m] & 0xFFFFu) == 0x3F80u) j = m * 2;       // bf16 1.0, even elem
                    if ((wd[m] >> 16)     == 0x3F80u) j = m * 2 + 1;   // odd elem
                }
                if (j >= 0)
                    evs[row] = (uint8_t)((u4i * 8 + j) | (corr_s[row] << 6));
            }
        }
    } else {
        // row = 64 f32 = 256 B = 16 uint4; 16 rows per iteration.
        const uint4* crow = (const uint4*)(chainw + (size_t)b * (TT * 64));
        const int f4i = tid & 15;
#pragma unroll 4
        for (int it = 0; it < 32; ++it) {
            int row = it * 16 + (tid >> 4);
            if (row < TT) {
                uint4 v = crow[row * 16 + f4i];
                int j = (v.x == 0x3F800000u) ? 0 : (v.y == 0x3F800000u) ? 1
                      : (v.z == 0x3F800000u) ? 2 : (v.w == 0x3F800000u) ? 3 : -1;
                if (j >= 0)
                    evs[row] = (uint8_t)((f4i * 4 + j) | (corr_s[row] << 6));
            }
        }
    }
    __syncthreads();

    // ---------- phase C: stable counting sort by k (LDS) ----------
    const int TWS = TT / 4;                       // 125
    const int t0 = w * TWS;
    int c = 0;
    for (int t = t0; t < t0 + TWS; ++t) c += ((evs[t] & 63) == lane);
    cnt[w][lane] = c;
    __syncthreads();

    if (w == 0) {
        int c0 = cnt[0][lane], c1 = cnt[1][lane], c2 = cnt[2][lane], c3 = cnt[3][lane];
        int tot = c0 + c1 + c2 + c3;
        int x = tot;
#pragma unroll
        for (int d = 1; d < 64; d <<= 1) {
            int o = __shfl_up(x, d);
            if (lane >= d) x += o;
        }
        int excl = x - tot;
        segs[lane] = excl;
        sege[lane] = excl + tot;
        int s = excl;
        startw[0][lane] = s; s += c0;
        startw[1][lane] = s; s += c1;
        startw[2][lane] = s; s += c2;
        startw[3][lane] = s;
    }
    __syncthreads();

    int ptr = startw[w][lane];
    for (int t = t0; t < t0 + TWS; ++t) {
        uint8_t e = evs[t];
        if ((e & 63) == lane) lst[ptr++] = (uint16_t)(t | ((e >> 6) << 9));
    }
    __syncthreads();

    // ---------- phase D: per-k scalar HMM filter (wave 0) ----------
    if (w == 0) {
        const int k = lane;
        float g0 = g0s[k], g1 = g1s[k], t10 = t10s[k], t11 = t11s[k];
        float dg = g1 - g0, dt = t11 - t10, g1c = 1.f - g1;
        float p1 = p1s[k];
        int e_ = sege[k];
        for (int i = segs[k]; i < e_; ++i) {
            int ee = lst[i];
            int t = ee & 511;
            int y = (ee >> 9) & 1;
            float pe1 = fmaf(p1, dg, g0);
            float pe0 = 1.f - pe1;
            float o0 = __logf(pe0), o1 = __logf(pe1);
            float gy  = y ? g1  : g1c;
            float pyy = y ? pe1 : pe0;
            float w1 = p1 * gy / pyy;
            p1 = fmaf(w1, dt, t10);
            out_s[t][0] = o0;
            out_s[t][1] = o1;
        }
    }
    __syncthreads();

    // ---------- phase E: coalesced store (500 float2 = 4000 B = 250 uint4) ----------
    uint4* dst = (uint4*)(out + (size_t)b * TT);  // byte offset b*4000, 16B-aligned
    const uint4* src = (const uint4*)out_s;
    for (int i = tid; i < 250; i += 256) dst[i] = src[i];
}

extern "C" void kernel_launch(void* const* d_in, const int* in_sizes, int n_in,
                              void* d_out, int out_size, void* d_ws, size_t ws_size,
                              hipStream_t stream) {
    // Identify inputs by flat element count (robust to ordering).
    const void* p_corr = nullptr, *p_chain = nullptr, *p_embd = nullptr,
              * p_Wf = nullptr, *p_bias = nullptr;
    for (int i = 0; i < n_in; ++i) {
        switch (in_sizes[i]) {
            case BB * TT:        p_corr  = d_in[i]; break;   // 256000
            case BB * TT * KK:   p_chain = d_in[i]; break;   // 16384000
            case KK * DD:        p_embd  = d_in[i]; break;   // 4096
            case 5 * DD:         p_Wf    = d_in[i]; break;   // 320
            case 5:              p_bias  = d_in[i]; break;
            default: break;
        }
    }
    if (!p_corr)  p_corr  = d_in[0];
    if (!p_chain) p_chain = d_in[1];
    if (!p_embd)  p_embd  = d_in[2];
    if (!p_Wf)    p_Wf    = d_in[3];
    if (!p_bias)  p_bias  = d_in[4];
    (void)d_ws; (void)ws_size; (void)out_size;

    bkt_fused<<<BB, 256, 0, stream>>>((const int*)p_corr,
                                      (const uint32_t*)p_chain,
                                      (const float*)p_embd,
                                      (const float*)p_Wf,
                                      (const float*)p_bias,
                                      (float2*)d_out);
}

// Round 7
// 32.163 us; speedup vs baseline: 1.5940x; 1.5940x over previous
//
#include <hip/hip_runtime.h>
#include <stdint.h>

#define BB 512
#define TT 500
#define KK 64
#define DD 64
#define NTH 1024
#define NW 16            // waves per block
#define TWS 32           // ceil(TT/NW)

// One 1024-thread block per batch element b. Zero global scratch.
// chain dtype (bf16 vs f32) sniffed per-wave from its first 256 B:
//   f32 one-hot row = 64 words, exactly 1 nonzero; bf16 = rows 0,1 -> 2 nonzero.
__launch_bounds__(NTH, 8)
__global__ void bkt_fused(const int* __restrict__ corr,
                          const uint32_t* __restrict__ chainw,
                          const float* __restrict__ embd,
                          const float* __restrict__ Wf,
                          const float* __restrict__ bias,
                          float2* __restrict__ out) {
    __shared__ int corr_s[TT];
    __shared__ uint8_t evs[TT];
    __shared__ float g0s[KK], g1s[KK], t10s[KK], t11s[KK], p1s[KK];
    __shared__ int cnt[NW][KK];
    __shared__ int startw[NW][KK];
    __shared__ int segs[KK], sege[KK];
    __shared__ uint16_t lst[TT];
    __shared__ __align__(16) float out_s[TT][2];

    const int b = blockIdx.x;
    const int tid = threadIdx.x;
    const int w = tid >> 6, lane = tid & 63;

    // ---------- per-wave dtype sniff (ballot broadcasts; no barrier needed) ----------
    uint32_t sv = chainw[lane];
    unsigned long long sm = __ballot(sv != 0u);
    const bool isb = (__popcll(sm) >= 2);

    // ---------- corr staging (1 load, independent) ----------
    if (tid < TT) corr_s[tid] = corr[b * TT + tid];

    // ---------- phase B: one-hot detect over chain[b] (4-8 independent loads/thread) ----------
    if (isb) {
        const uint4* cb = (const uint4*)(chainw + (size_t)b * (TT * 32));   // 128 B rows
#pragma unroll
        for (int it = 0; it < 4; ++it) {
            int f = it * NTH + tid;                 // flat uint4 index, 0..3999
            if (f < TT * 8) {
                uint4 v = cb[f];
                int row = f >> 3, u = f & 7;
                uint32_t wd[4] = {v.x, v.y, v.z, v.w};
                int j = -1;
#pragma unroll
                for (int q = 0; q < 4; ++q) {
                    if ((wd[q] & 0xFFFFu) == 0x3F80u) j = q * 2;
                    if ((wd[q] >> 16)     == 0x3F80u) j = q * 2 + 1;
                }
                if (j >= 0) evs[row] = (uint8_t)(u * 8 + j);
            }
        }
    } else {
        const uint4* cb = (const uint4*)(chainw + (size_t)b * (TT * 64));   // 256 B rows
#pragma unroll
        for (int it = 0; it < 8; ++it) {
            int f = it * NTH + tid;                 // flat uint4 index, 0..7999
            if (f < TT * 16) {
                uint4 v = cb[f];
                int row = f >> 4, u = f & 15;
                int j = (v.x == 0x3F800000u) ? 0 : (v.y == 0x3F800000u) ? 1
                      : (v.z == 0x3F800000u) ? 2 : (v.w == 0x3F800000u) ? 3 : -1;
                if (j >= 0) evs[row] = (uint8_t)(u * 4 + j);
            }
        }
    }

    // ---------- params: lanes 0..63, weights straight from global/L2 ----------
    if (tid < KK) {
        const int k = tid;
        float l0 = bias[0], l1 = bias[1], l2 = bias[2], l3 = bias[3], l4 = bias[4];
        const float4* er = (const float4*)(embd + k * DD);
        const float4* w0 = (const float4*)(Wf + 0 * DD);
        const float4* w1 = (const float4*)(Wf + 1 * DD);
        const float4* w2 = (const float4*)(Wf + 2 * DD);
        const float4* w3 = (const float4*)(Wf + 3 * DD);
        const float4* w4 = (const float4*)(Wf + 4 * DD);
#pragma unroll 4
        for (int d4 = 0; d4 < DD / 4; ++d4) {
            float4 e = er[d4];
            float4 a;
            a = w0[d4]; l0 = fmaf(e.x,a.x,fmaf(e.y,a.y,fmaf(e.z,a.z,fmaf(e.w,a.w,l0))));
            a = w1[d4]; l1 = fmaf(e.x,a.x,fmaf(e.y,a.y,fmaf(e.z,a.z,fmaf(e.w,a.w,l1))));
            a = w2[d4]; l2 = fmaf(e.x,a.x,fmaf(e.y,a.y,fmaf(e.z,a.z,fmaf(e.w,a.w,l2))));
            a = w3[d4]; l3 = fmaf(e.x,a.x,fmaf(e.y,a.y,fmaf(e.z,a.z,fmaf(e.w,a.w,l3))));
            a = w4[d4]; l4 = fmaf(e.x,a.x,fmaf(e.y,a.y,fmaf(e.z,a.z,fmaf(e.w,a.w,l4))));
        }
        auto sig = [](float x) { return 1.0f / (1.0f + __expf(-x)); };
        t10s[k] = sig( 2.f * l0);   // p(s'=1 | s=0)
        t11s[k] = sig(-2.f * l1);   // p(s'=1 | s=1)
        g0s[k]  = sig( 2.f * l2);   // p(y=1 | s=0)
        g1s[k]  = sig(-2.f * l3);   // p(y=1 | s=1)
        p1s[k]  = sig( 2.f * l4);   // p(s=1) initial
    }
    __syncthreads();   // evs, corr_s, params all ready

    // ---------- phase C: stable counting sort by k (16 waves x 32-t slices) ----------
    const int t0 = w * TWS;
    const int t1 = (t0 + TWS < TT) ? t0 + TWS : TT;
    int c = 0;
    for (int t = t0; t < t1; ++t) c += (evs[t] == lane);
    cnt[w][lane] = c;
    __syncthreads();

    if (w == 0) {
        int sum = 0;
#pragma unroll
        for (int q = 0; q < NW; ++q) { startw[q][lane] = sum; sum += cnt[q][lane]; }
        int tot = sum;
        int x = tot;
#pragma unroll
        for (int d = 1; d < 64; d <<= 1) {
            int o = __shfl_up(x, d);
            if (lane >= d) x += o;
        }
        int excl = x - tot;
        segs[lane] = excl;
        sege[lane] = excl + tot;
#pragma unroll
        for (int q = 0; q < NW; ++q) startw[q][lane] += excl;
    }
    __syncthreads();

    int ptr = startw[w][lane];
    for (int t = t0; t < t1; ++t)
        if (evs[t] == lane) lst[ptr++] = (uint16_t)t;
    __syncthreads();

    // ---------- phase D: per-k scalar HMM filter (wave 0) ----------
    if (w == 0) {
        const int k = lane;
        float g0 = g0s[k], g1 = g1s[k], t10 = t10s[k], t11 = t11s[k];
        float dg = g1 - g0, dt = t11 - t10, g1c = 1.f - g1;
        float p1 = p1s[k];
        const int e_ = sege[k];
        for (int i = segs[k]; i < e_; ++i) {
            int t = lst[i];
            int y = corr_s[t];
            float pe1 = fmaf(p1, dg, g0);
            float pe0 = 1.f - pe1;
            out_s[t][0] = __logf(pe0);
            out_s[t][1] = __logf(pe1);
            float gy  = y ? g1  : g1c;
            float pyy = y ? pe1 : pe0;
            float w1 = p1 * gy / pyy;
            p1 = fmaf(w1, dt, t10);
        }
    }
    __syncthreads();

    // ---------- phase E: coalesced store (500 float2 = 4000 B = 250 uint4) ----------
    uint4* dst = (uint4*)(out + (size_t)b * TT);
    const uint4* src = (const uint4*)out_s;
    if (tid < 250) dst[tid] = src[tid];
}

extern "C" void kernel_launch(void* const* d_in, const int* in_sizes, int n_in,
                              void* d_out, int out_size, void* d_ws, size_t ws_size,
                              hipStream_t stream) {
    // Identify inputs by flat element count (robust to ordering).
    const void* p_corr = nullptr, *p_chain = nullptr, *p_embd = nullptr,
              * p_Wf = nullptr, *p_bias = nullptr;
    for (int i = 0; i < n_in; ++i) {
        switch (in_sizes[i]) {
            case BB * TT:        p_corr  = d_in[i]; break;   // 256000
            case BB * TT * KK:   p_chain = d_in[i]; break;   // 16384000
            case KK * DD:        p_embd  = d_in[i]; break;   // 4096
            case 5 * DD:         p_Wf    = d_in[i]; break;   // 320
            case 5:              p_bias  = d_in[i]; break;
            default: break;
        }
    }
    if (!p_corr)  p_corr  = d_in[0];
    if (!p_chain) p_chain = d_in[1];
    if (!p_embd)  p_embd  = d_in[2];
    if (!p_Wf)    p_Wf    = d_in[3];
    if (!p_bias)  p_bias  = d_in[4];
    (void)d_ws; (void)ws_size; (void)out_size;

    bkt_fused<<<BB, NTH, 0, stream>>>((const int*)p_corr,
                                      (const uint32_t*)p_chain,
                                      (const float*)p_embd,
                                      (const float*)p_Wf,
                                      (const float*)p_bias,
                                      (float2*)d_out);
}